// Round 2
// baseline (670.195 us; speedup 1.0000x reference)
//
#include <hip/hip_runtime.h>
#include <math.h>

#define B_ 32
#define DIM_ 4096
#define NKV_ 8
#define HD_ 128
#define T_ 2048
#define KS_ 16
#define QKV_ROWS_ 6144
#define O_ROWS_ 4096
#define NCHUNK_ 16          // t-chunks per batch (128 t each), 4 waves -> 64 splits
#define NSPLITW_ 64         // splits per (b,kv) = NCHUNK_*4 waves

// ws layout (float offsets)
#define Q_OFF    0
#define KNEW_OFF (Q_OFF + B_*DIM_)
#define VNEW_OFF (KNEW_OFF + B_*NKV_*HD_)
#define AO_OFF   (VNEW_OFF + B_*NKV_*HD_)
#define PQKV_OFF (AO_OFF + B_*DIM_)
#define PO_OFF   (PQKV_OFF + KS_*QKV_ROWS_*B_)
#define OPART_OFF (PO_OFF + KS_*O_ROWS_*B_)
#define ML_OFF   (OPART_OFF + B_*NKV_*NSPLITW_*4*HD_)
// ML: B*NKV*64 splits*4 reps*2 floats

__device__ __forceinline__ void fma4(float4& a, const float4& x, float w) {
    a.x = fmaf(x.x, w, a.x); a.y = fmaf(x.y, w, a.y);
    a.z = fmaf(x.z, w, a.z); a.w = fmaf(x.w, w, a.w);
}

// C[b][row] partial = sum_{k in chunk} X[b][k] * W[row][k]
// register double-buffer: tile kt+1 loads issue before compute of kt,
// vmcnt wait lands at next iteration's LDS store (latency hidden under FMAs)
template<int NROWS>
__global__ __launch_bounds__(256) void gemm_split(
    const float* __restrict__ X, const float* __restrict__ W0,
    const float* __restrict__ W1, const float* __restrict__ W2,
    float* __restrict__ part)
{
    __shared__ float xs[32][36];
    __shared__ float wsh[32][132];
    const int rb = blockIdx.x, ks = blockIdx.y;
    const int row0 = rb * 128;
    const float* W; int wr0;
    if (NROWS == 4096 || row0 < 4096) { W = W0; wr0 = row0; }
    else if (row0 < 5120)             { W = W1; wr0 = row0 - 4096; }
    else                              { W = W2; wr0 = row0 - 5120; }
    const int tid = threadIdx.x;
    const int rt = tid & 31, bt = tid >> 5;
    float4 acc[4];
    acc[0] = acc[1] = acc[2] = acc[3] = make_float4(0.f,0.f,0.f,0.f);
    const int kc0 = ks * 256;
    const int xb = tid >> 3, xkq = tid & 7;   // xb doubles as W row base
    float4 xpf, wpf[4];
    xpf = *(const float4*)(X + xb * DIM_ + kc0 + xkq * 4);
    #pragma unroll
    for (int j = 0; j < 4; ++j)
        wpf[j] = *(const float4*)(W + (wr0 + xb + 32*j) * DIM_ + kc0 + xkq * 4);
    for (int kt = 0; kt < 8; ++kt) {
        __syncthreads();
        xs[xkq*4+0][xb] = xpf.x; xs[xkq*4+1][xb] = xpf.y;
        xs[xkq*4+2][xb] = xpf.z; xs[xkq*4+3][xb] = xpf.w;
        #pragma unroll
        for (int j = 0; j < 4; ++j) {
            const int r = xb + 32*j;
            wsh[xkq*4+0][r] = wpf[j].x; wsh[xkq*4+1][r] = wpf[j].y;
            wsh[xkq*4+2][r] = wpf[j].z; wsh[xkq*4+3][r] = wpf[j].w;
        }
        __syncthreads();
        if (kt < 7) {
            const int kc = kc0 + (kt + 1) * 32;
            xpf = *(const float4*)(X + xb * DIM_ + kc + xkq * 4);
            #pragma unroll
            for (int j = 0; j < 4; ++j)
                wpf[j] = *(const float4*)(W + (wr0 + xb + 32*j) * DIM_ + kc + xkq * 4);
        }
        #pragma unroll
        for (int k = 0; k < 32; ++k) {
            float4 xv = *(const float4*)&xs[k][bt*4];
            float4 wv = *(const float4*)&wsh[k][rt*4];
            fma4(acc[0], xv, wv.x);
            fma4(acc[1], xv, wv.y);
            fma4(acc[2], xv, wv.z);
            fma4(acc[3], xv, wv.w);
        }
    }
    #pragma unroll
    for (int j = 0; j < 4; ++j) {
        const int row = row0 + rt * 4 + j;
        *(float4*)(part + (ks * NROWS + row) * 32 + bt * 4) = acc[j];
    }
}

__global__ __launch_bounds__(256) void reduce_rope(
    const float* __restrict__ part, const float* __restrict__ fc,
    const float* __restrict__ fs, float* __restrict__ qout,
    float* __restrict__ kout, float* __restrict__ vout)
{
    const int t = blockIdx.x * 256 + threadIdx.x;
    const int b = t & 31;
    const int row0 = (t >> 5) * 2;
    float s0 = 0.f, s1 = 0.f;
    #pragma unroll
    for (int ks = 0; ks < KS_; ++ks) {
        const float* p = part + (ks * QKV_ROWS_ + row0) * 32 + b;
        s0 += p[0];
        s1 += p[32];
    }
    if (row0 < 5120) {
        const int i = (row0 & 127) >> 1;
        const float c = fc[i], s = fs[i];
        const float o0 = s0 * c - s1 * s;
        const float o1 = s0 * s + s1 * c;
        if (row0 < 4096) {
            qout[b * 4096 + row0]     = o0;
            qout[b * 4096 + row0 + 1] = o1;
        } else {
            const int lr = row0 - 4096;
            kout[b * 1024 + lr]     = o0;
            kout[b * 1024 + lr + 1] = o1;
        }
    } else {
        const int lr = row0 - 5120;
        vout[b * 1024 + lr]     = s0;
        vout[b * 1024 + lr + 1] = s1;
    }
}

// decode attention, contiguity-first layout:
// block = (b, chunk of 128 t) covering ALL 8 kv heads -> per t the wave
// reads a fully contiguous 4 KB row of cache_k/cache_v.
// Each wave owns a private 32-t sub-split (own m,l,Opart; no cross-wave
// reduction). lane = (kvl = ln>>3, dsl = ln&7): 16 d-floats per lane.
__global__ __launch_bounds__(256, 2) void attn_split(
    const float* __restrict__ q, const float* __restrict__ knew,
    const float* __restrict__ vnew, const float* __restrict__ ck,
    const float* __restrict__ cv, float* __restrict__ opart,
    float* __restrict__ ml)
{
    __shared__ float sct[4][32 * 33];   // per-wave [pair=kv*4+rep][33] probs
    const int chunk = blockIdx.x & 15;
    const int b     = blockIdx.x >> 4;
    const int tid = threadIdx.x;
    const int w  = tid >> 6, ln = tid & 63;
    const int kvl = ln >> 3, dsl = ln & 7;
    const int t0 = chunk * 128 + w * 32;
    const int split = chunk * 4 + w;
    const float scale = 0.08838834764831845f;  // 128^-0.5
    float* ss = sct[w];

    // ---- phase A: scores for this wave's 32 t, all 32 heads ----
    float4 qr[4][4];
    #pragma unroll
    for (int r = 0; r < 4; ++r) {
        const float* qp = q + b * 4096 + (kvl * 4 + r) * 128 + dsl * 16;
        #pragma unroll
        for (int j = 0; j < 4; ++j) qr[r][j] = *(const float4*)(qp + j * 4);
    }
    const float* ckb = ck + (size_t)b * (2048 * 1024) + kvl * 128 + dsl * 16;
    const float* knb = knew + (b * 8 + kvl) * 128 + dsl * 16;

    for (int tt = 0; tt < 32; tt += 2) {
        float4 ka[2][4];
        #pragma unroll
        for (int u = 0; u < 2; ++u) {
            const int gt = t0 + tt + u;
            const float* kp = (gt == 2047) ? knb : (ckb + (size_t)gt * 1024);
            #pragma unroll
            for (int j = 0; j < 4; ++j) ka[u][j] = *(const float4*)(kp + j * 4);
        }
        #pragma unroll
        for (int u = 0; u < 2; ++u) {
            float d[4];
            #pragma unroll
            for (int r = 0; r < 4; ++r) {
                float s = 0.f;
                #pragma unroll
                for (int j = 0; j < 4; ++j) {
                    s = fmaf(ka[u][j].x, qr[r][j].x, s);
                    s = fmaf(ka[u][j].y, qr[r][j].y, s);
                    s = fmaf(ka[u][j].z, qr[r][j].z, s);
                    s = fmaf(ka[u][j].w, qr[r][j].w, s);
                }
                s += __shfl_xor(s, 1);
                s += __shfl_xor(s, 2);
                s += __shfl_xor(s, 4);
                d[r] = s * scale;
            }
            // lanes dsl=0..3 each store rep dsl; banks (kvl*4+dsl+t)%32 distinct
            float out = d[0];
            const int dr = dsl & 3;
            if (dr == 1) out = d[1];
            if (dr == 2) out = d[2];
            if (dr == 3) out = d[3];
            if (dsl < 4) ss[(kvl * 4 + dsl) * 33 + tt + u] = out;
        }
    }
    __syncthreads();   // compiler ordering fence for cross-lane LDS handoff

    // ---- phase B: per-wave partial softmax, lane = pair (32 active) ----
    if (ln < 32) {
        float mx = -1e30f;
        #pragma unroll
        for (int t = 0; t < 32; ++t) mx = fmaxf(mx, ss[ln * 33 + t]);
        float sum = 0.f;
        #pragma unroll
        for (int t = 0; t < 32; ++t) {
            const float p = __expf(ss[ln * 33 + t] - mx);
            ss[ln * 33 + t] = p;
            sum += p;
        }
        const int kvp = ln >> 2, rp = ln & 3;
        *(float2*)(ml + (size_t)(((b * 8 + kvp) * 64 + split) * 4 + rp) * 2)
            = make_float2(mx, sum);
    }
    __syncthreads();

    // ---- phase C: partial O = P V, contiguous V stream ----
    float4 acc[4][4];
    #pragma unroll
    for (int r = 0; r < 4; ++r)
        #pragma unroll
        for (int j = 0; j < 4; ++j) acc[r][j] = make_float4(0.f,0.f,0.f,0.f);
    const float* cvb = cv + (size_t)b * (2048 * 1024) + kvl * 128 + dsl * 16;
    const float* vnb = vnew + (b * 8 + kvl) * 128 + dsl * 16;
    for (int tt = 0; tt < 32; tt += 2) {
        float4 va[2][4];
        #pragma unroll
        for (int u = 0; u < 2; ++u) {
            const int gt = t0 + tt + u;
            const float* vp = (gt == 2047) ? vnb : (cvb + (size_t)gt * 1024);
            #pragma unroll
            for (int j = 0; j < 4; ++j) va[u][j] = *(const float4*)(vp + j * 4);
        }
        #pragma unroll
        for (int u = 0; u < 2; ++u) {
            #pragma unroll
            for (int r = 0; r < 4; ++r) {
                const float p = ss[(kvl * 4 + r) * 33 + tt + u];  // 8-lane bcast
                #pragma unroll
                for (int j = 0; j < 4; ++j) fma4(acc[r][j], va[u][j], p);
            }
        }
    }
    float* ob = opart + (size_t)(((b * 8 + kvl) * 64 + split) * 4) * 128 + dsl * 16;
    #pragma unroll
    for (int r = 0; r < 4; ++r)
        #pragma unroll
        for (int j = 0; j < 4; ++j)
            *(float4*)(ob + r * 128 + j * 4) = acc[r][j];
}

// merge 64 sub-splits with log-sum-exp weights
__global__ __launch_bounds__(128) void attn_merge(
    const float* __restrict__ opart, const float* __restrict__ ml,
    float* __restrict__ ao)
{
    const int bk = blockIdx.x;          // b*8+kv
    const int tid = threadIdx.x;
    const int r = tid >> 5, dq = tid & 31;
    float M = -1e30f;
    #pragma unroll 8
    for (int sp = 0; sp < NSPLITW_; ++sp)
        M = fmaxf(M, ml[(size_t)((bk * 64 + sp) * 4 + r) * 2]);
    float L = 0.f;
    float4 o = make_float4(0.f, 0.f, 0.f, 0.f);
    #pragma unroll 4
    for (int sp = 0; sp < NSPLITW_; ++sp) {
        const float2 mlv = *(const float2*)(ml + (size_t)((bk * 64 + sp) * 4 + r) * 2);
        const float wgt = __expf(mlv.x - M);
        L += mlv.y * wgt;
        const float4 v = *(const float4*)(opart
            + (size_t)((bk * 64 + sp) * 4 + r) * 128 + dq * 4);
        fma4(o, v, wgt);
    }
    const float inv = 1.f / L;
    o.x *= inv; o.y *= inv; o.z *= inv; o.w *= inv;
    *(float4*)(ao + bk * 512 + r * 128 + dq * 4) = o;
}

__global__ __launch_bounds__(256) void reduce_out(
    const float* __restrict__ part, float* __restrict__ out)
{
    const int t = blockIdx.x * 256 + threadIdx.x;
    const int b = t & 31, row = t >> 5;
    float s = 0.f;
    #pragma unroll
    for (int ks = 0; ks < KS_; ++ks)
        s += part[(ks * O_ROWS_ + row) * 32 + b];
    out[b * 4096 + row] = s;
}

extern "C" void kernel_launch(void* const* d_in, const int* in_sizes, int n_in,
                              void* d_out, int out_size, void* d_ws, size_t ws_size,
                              hipStream_t stream)
{
    const float* x  = (const float*)d_in[0];
    const float* fc = (const float*)d_in[1];
    const float* fs = (const float*)d_in[2];
    const float* wq = (const float*)d_in[3];
    const float* wk = (const float*)d_in[4];
    const float* wv = (const float*)d_in[5];
    const float* wo = (const float*)d_in[6];
    const float* ck = (const float*)d_in[7];
    const float* cv = (const float*)d_in[8];
    float* ws    = (float*)d_ws;
    float* q     = ws + Q_OFF;
    float* knew  = ws + KNEW_OFF;
    float* vnew  = ws + VNEW_OFF;
    float* ao    = ws + AO_OFF;
    float* pqkv  = ws + PQKV_OFF;
    float* po    = ws + PO_OFF;
    float* opart = ws + OPART_OFF;
    float* mlp   = ws + ML_OFF;

    gemm_split<QKV_ROWS_><<<dim3(48, 16), 256, 0, stream>>>(x, wq, wk, wv, pqkv);
    reduce_rope<<<384, 256, 0, stream>>>(pqkv, fc, fs, q, knew, vnew);
    attn_split<<<512, 256, 0, stream>>>(q, knew, vnew, ck, cv, opart, mlp);
    attn_merge<<<256, 128, 0, stream>>>(opart, mlp, ao);
    gemm_split<O_ROWS_><<<dim3(32, 16), 256, 0, stream>>>(ao, wo, wo, wo, po);
    reduce_out<<<512, 256, 0, stream>>>(po, (float*)d_out);
}